// Round 11
// baseline (237.399 us; speedup 1.0000x reference)
//
#include <hip/hip_runtime.h>

// ---------------------------------------------------------------------------
// NearestSim: out[t] = -cos(q_t, items[argmax_j q_t . items_j])
// T=16384, M=4096, C=512, fp32 in/out.
// R22 = R17 machinery (K-sub-phase dbuf staging, counted vmcnt barriers,
//       med3/ds_swizzle epilogue) on a 128q x 256i block (512 thr, 8 waves,
//       2x4): wave pair (wr=0/1, same wc) reads IDENTICAL B lines in the
//       same kstep window on the same CU -> L1 absorbs the duplicate ->
//       L2 B-request volume ~halves. A-staging requests also halve.
//       Model: every prior round left B requests invariant at 1GB; sustained
//       L2 ~14.7 TB/s is the binding constraint (explains R17/R18/R19/R21).
//  - 16 waves/CU (2 blocks x 8 waves) needs <=128 VGPR: 64 acc + 16 aC
//    (no A-prefetch; 4 waves/SIMD TLP covers LDS latency) + 32 B (2-set
//    rotation: load b(k+2) into the set consumed at k) + ~14 addr = ~126.
//    __launch_bounds__(512,4) pins the cap; spill shows as WRITE_SIZE.
// ---------------------------------------------------------------------------

#define TQ 16384
#define MI 4096
#define CD 512
#define NIS 16          // item splits; block covers 256 items
#define BM 128          // block query rows (2 x 64 per wave-row)

typedef _Float16 half8   __attribute__((ext_vector_type(8)));
typedef _Float16 half4_t __attribute__((ext_vector_type(4)));
typedef float    float4t __attribute__((ext_vector_type(4)));

// workspace layout (bytes)
#define QH_OFF   (0u)
#define QH_BYTES ((unsigned)TQ * CD * 2u)          // 16 MB fp16 queries (row-major)
#define IH_OFF   (QH_OFF + QH_BYTES)
#define IH_BYTES ((unsigned)MI * CD * 2u)          // 4 MB fp16 items (fragment order)
#define PART_OFF (IH_OFF + IH_BYTES)
#define PART_BYTES ((unsigned)TQ * 64u * 8u)       // 8 MB: 64 float2 / query
// total 28 MB

__device__ __forceinline__ void lds_load16(const void* g, void* l) {
  __builtin_amdgcn_global_load_lds(
      (const __attribute__((address_space(1))) void*)g,
      (__attribute__((address_space(3))) void*)l, 16, 0, 0);
}

template <int SWZ>
__device__ __forceinline__ float swz_f(float x) {
  return __int_as_float(__builtin_amdgcn_ds_swizzle(__float_as_int(x), SWZ));
}

// ---------------- kernel 1: fp32 -> fp16 conversion -------------------------
// Q: row-major half4 copy. Items: fragment order (chunk = (tile16*16+kk)*64
// + lane; lane = quad*16+l15 holds row tile16*16+l15, cols kk*32+quad*8..+8).
__global__ __launch_bounds__(256) void convert_kernel(
    const float* __restrict__ q, const float* __restrict__ it,
    char* __restrict__ ws) {
  const int idx = blockIdx.x * 256 + threadIdx.x;
  const int QV = TQ * CD / 4;   // Q: one half4 per thread
  const int IC = MI * CD / 8;   // items: one 16B chunk per thread
  if (idx < QV) {
    float4 v = ((const float4*)q)[idx];
    half4_t h = {(_Float16)v.x, (_Float16)v.y, (_Float16)v.z, (_Float16)v.w};
    ((half4_t*)(ws + QH_OFF))[idx] = h;
  }
  const int ic = idx - QV;
  if (ic >= 0 && ic < IC) {
    const int tile = ic >> 10;          // 1024 chunks per 16-row tile
    const int rem  = ic & 1023;
    const int kk   = rem >> 6;
    const int lane = rem & 63;
    const int row  = tile * 16 + (lane & 15);
    const int col  = kk * 32 + (lane >> 4) * 8;
    const float4* s = (const float4*)(it + (size_t)row * CD + col);
    float4 v0 = s[0], v1 = s[1];
    half8 h = {(_Float16)v0.x, (_Float16)v0.y, (_Float16)v0.z, (_Float16)v0.w,
               (_Float16)v1.x, (_Float16)v1.y, (_Float16)v1.z, (_Float16)v1.w};
    *(half8*)(ws + IH_OFF + (size_t)ic * 16) = h;
  }
}

// ---------------- kernel 2: pipelined fused GEMM + packed top-2 -------------
// grid (TQ/128, NIS), block 512 = 8 waves: wr = wave>>2 (q-half), wc = wave&3
// (item group). Wave tile 64q x 64i (4x4 MFMAs of 16x16x32, 64 acc).
// A image: 4 sub-phases of K=128, 128 rows x 256B = 32KB each, dbuf 64KB.
// B direct global; wave pairs (wr=0/1) share B lines via L1.
// LDS image (per phase buf): row r (0..127) at r*256; 16 chunks of 16B per
// row; phys chunk = logical c ^ (r&15).
// Staging (4 instr/phase): instr j, thread t -> dest = buf*32768+j*8192+t*16
//   row = j*32 + (t>>4), phys chunk = t&15,
//   logical c = (t&15) ^ (row&15) = (t&15) ^ ((t>>4)&15)  [j*32 ≡ 0 mod 16].
__global__ __launch_bounds__(512, 4) void score_kernel(char* __restrict__ ws) {
  __shared__ __align__(16) char sA[2][32768];  // 64 KB total

  const int tid  = threadIdx.x;
  const int lane = tid & 63;
  const int wave = tid >> 6;       // 0..7
  const int quad = lane >> 4;
  const int l15  = lane & 15;
  const int wr   = wave >> 2;      // q-half 0/1
  const int wc   = wave & 3;       // item group 0..3
  const int qtile = blockIdx.x;    // 0..127; XCD = qtile%8
  const int isplit = blockIdx.y;

  // staging source base: + j*32768 + phase*256
  const char* Qbase = ws + QH_OFF + (size_t)qtile * BM * 1024;
  const char* gQ = Qbase + (tid >> 4) * 1024 +
                   (((tid & 15) ^ ((tid >> 4) & 15)) * 16);
  const int ldst = tid * 16;  // + buf*32768 + j*8192

  // B stream: tile(ni) = isplit*16 + wc*4 + ni  (wr pair shares these lines)
  const char* Ibase = ws + IH_OFF;
  int bOff[4];
#pragma unroll
  for (int ni = 0; ni < 4; ++ni)
    bOff[ni] = ((isplit * 16 + wc * 4 + ni) << 14) + lane * 16;

  // A fragment: byte = buf*32768 + wr*16384 + mi*4096 + l15*256
  //                    + ((kl*4+quad) ^ l15)*16
  const int aBase = wr * 16384 + l15 * 256;

  float4t acc[4][4];
#pragma unroll
  for (int mi = 0; mi < 4; ++mi)
#pragma unroll
    for (int ni = 0; ni < 4; ++ni) acc[mi][ni] = (float4t){0.f, 0.f, 0.f, 0.f};

  half8 aC[4], b0[4], b1[4];

#define STAGE(ph, buf)                                                    \
  {                                                                       \
    _Pragma("unroll") for (int j = 0; j < 4; ++j)                         \
      lds_load16(gQ + j * 32768 + (ph) * 256,                             \
                 (char*)sA + (buf) * 32768 + j * 8192 + ldst);            \
  }

  STAGE(0, 0);
  STAGE(1, 1);
  __builtin_amdgcn_sched_barrier(0);  // pin: B prologue issues AFTER staging

  // B prologue: k0 -> b0, k1 -> b1 (8 loads, stay in flight)
#pragma unroll
  for (int ni = 0; ni < 4; ++ni) b0[ni] = *(const half8*)(Ibase + bOff[ni]);
#pragma unroll
  for (int ni = 0; ni < 4; ++ni)
    b1[ni] = *(const half8*)(Ibase + bOff[ni] + 1024);

  // 16 outstanding; vmcnt(12) drains the 4 oldest = stage(0).
  asm volatile("s_waitcnt vmcnt(12)\n\ts_barrier" ::: "memory");

  // WB: stage group is older than the 16 B loads of the preceding KPHASE;
  // vmcnt(8) -> stage done, 8 newest B prefetches stay in flight.
#define WB() asm volatile("s_waitcnt vmcnt(8)\n\ts_barrier" ::: "memory")

#define KPHASE(ph, buf)                                                   \
  {                                                                       \
    const char* sB = (const char*)sA + (buf) * 32768 + aBase;             \
    _Pragma("unroll") for (int mi = 0; mi < 4; ++mi)                      \
      aC[mi] = *(const half8*)(sB + mi * 4096 + ((quad ^ l15) << 4));     \
    _Pragma("unroll") for (int kl = 0; kl < 4; ++kl) {                    \
      const int kk = (ph) * 4 + kl;                                       \
      half8* bs = (kk & 1) ? b1 : b0;                                     \
      __builtin_amdgcn_s_setprio(1);                                      \
      _Pragma("unroll") for (int mi = 0; mi < 4; ++mi)                    \
        _Pragma("unroll") for (int ni = 0; ni < 4; ++ni)                  \
          acc[mi][ni] = __builtin_amdgcn_mfma_f32_16x16x32_f16(           \
              aC[mi], bs[ni], acc[mi][ni], 0, 0, 0);                      \
      __builtin_amdgcn_s_setprio(0);                                      \
      if (kk + 2 < 16) {  /* rotate-load b(kk+2) into the consumed set */ \
        _Pragma("unroll") for (int ni = 0; ni < 4; ++ni)                  \
          bs[ni] = *(const half8*)(Ibase + bOff[ni] + 2048);              \
      }                                                                   \
      if (kl + 1 < 4) {   /* a-frags for next kstep (same regs, WAR ok) */\
        const int cN = ((((kl + 1) << 2) + quad) ^ l15) << 4;             \
        _Pragma("unroll") for (int mi = 0; mi < 4; ++mi)                  \
          aC[mi] = *(const half8*)(sB + mi * 4096 + cN);                  \
      }                                                                   \
      _Pragma("unroll") for (int ni = 0; ni < 4; ++ni) bOff[ni] += 1024;  \
    }                                                                     \
  }

  KPHASE(0, 0);
  WB();             // stage(1) done; newest B prefetches stay in flight
  STAGE(2, 0);      // b0 image free: all waves passed the barrier
  KPHASE(1, 1);
  WB();             // stage(2) done
  STAGE(3, 1);
  KPHASE(2, 0);
  WB();             // stage(3) done
  KPHASE(3, 1);

#undef KPHASE
#undef WB
#undef STAGE

  // ---- epilogue: packed (score | 12-bit global idx) top-2 per query row ----
  // C row = quad*4+r (within wave's 64q), col = l15.
  // item = isplit*256 + wc*64 + ni*16 + l15.
  float t1[16], t2[16];

  const int locBase = isplit * 256 + wc * 64 + l15;
#pragma unroll
  for (int ni = 0; ni < 4; ++ni) {
    const int loc = locBase + ni * 16;
#pragma unroll
    for (int mi = 0; mi < 4; ++mi) {
#pragma unroll
      for (int r = 0; r < 4; ++r) {
        const int s = mi * 4 + r;
        const float pv = __int_as_float(
            (__float_as_int(acc[mi][ni][r]) & 0xFFFFF000) | loc);
        if (ni == 0) {
          t1[s] = pv;
          t2[s] = -1e30f;
        } else {
          t2[s] = __builtin_amdgcn_fmed3f(pv, t1[s], t2[s]);
          t1[s] = fmaxf(t1[s], pv);
        }
      }
    }
  }

  // 4-step butterfly across the 16-lane l15 group via ds_swizzle xor
  // patterns (BitMode: offset = (xor<<10)|0x1F). Disjoint partner sets:
  //   t2' = med3(t1, o1, max(t2, o2)) = max(min(t1,o1), max(t2,o2)).
#define BSTEP(SWZ)                                                       \
  {                                                                      \
    _Pragma("unroll") for (int s = 0; s < 16; ++s) {                     \
      const float o1 = swz_f<SWZ>(t1[s]);                                \
      const float o2 = swz_f<SWZ>(t2[s]);                                \
      t2[s] = __builtin_amdgcn_fmed3f(t1[s], o1, fmaxf(t2[s], o2));      \
      t1[s] = fmaxf(t1[s], o1);                                          \
    }                                                                    \
  }
  BSTEP(0x041F)   // xor 1
  BSTEP(0x081F)   // xor 2
  BSTEP(0x101F)   // xor 4
  BSTEP(0x201F)   // xor 8
#undef BSTEP

  // writer: l15 == 0; entry = isplit*4 + wc. 64 entries per query.
  if (l15 == 0) {
    float2* part = (float2*)(ws + PART_OFF);
    const int e = isplit * 4 + wc;
#pragma unroll
    for (int s = 0; s < 16; ++s) {
      const int qrow = qtile * BM + wr * 64 + (s >> 2) * 16 + quad * 4 +
                       (s & 3);
      part[(size_t)qrow * 64 + e] = make_float2(t1[s], t2[s]);
    }
  }
}

// ---------------- kernel 3: merge partials + exact fp32 rescue --------------
// one wave per query: 64 packed entries (1/lane) -> global fp16 top-2.
// If the packed gap exceeds 0.25 (>>5 sigma of fp16+quant score error),
// candidate 1 is certainly the true argmax: skip the 2nd gather entirely
// (wave-uniform branch). Otherwise exact fp32 re-score of both.
__global__ __launch_bounds__(256) void rescue_kernel(
    const float* __restrict__ q, const float* __restrict__ items,
    const char* __restrict__ ws, float* __restrict__ out) {
  const int wave = threadIdx.x >> 6;
  const int lane = threadIdx.x & 63;
  const int qrow = blockIdx.x * 4 + wave;

  const float2* part = (const float2*)(ws + PART_OFF);
  float2 ent = part[(size_t)qrow * 64 + lane];  // coalesced 512B burst
  float t1 = ent.x, t2 = ent.y;

#pragma unroll
  for (int m = 1; m < 64; m <<= 1) {
    const float o1 = __shfl_xor(t1, m, 64);
    const float o2 = __shfl_xor(t2, m, 64);
    const float mn = fminf(t1, o1);
    t1 = fmaxf(t1, o1);
    t2 = fmaxf(fmaxf(t2, o2), mn);
  }
  const int c1i = __float_as_int(t1) & 0xFFF;
  const int c2i = __float_as_int(t2) & 0xFFF;
  const bool need2 = (t1 - t2) < 0.25f;   // wave-uniform

  const float4* qp = (const float4*)(q + (size_t)qrow * CD);
  const float4* p1 = (const float4*)(items + (size_t)c1i * CD);
  float4 qa = qp[lane * 2], qb = qp[lane * 2 + 1];
  float4 xa = p1[lane * 2], xb = p1[lane * 2 + 1];

  float d1 = qa.x * xa.x + qa.y * xa.y + qa.z * xa.z + qa.w * xa.w +
             qb.x * xb.x + qb.y * xb.y + qb.z * xb.z + qb.w * xb.w;
  float qq = qa.x * qa.x + qa.y * qa.y + qa.z * qa.z + qa.w * qa.w +
             qb.x * qb.x + qb.y * qb.y + qb.z * qb.z + qb.w * qb.w;
  float i1 = xa.x * xa.x + xa.y * xa.y + xa.z * xa.z + xa.w * xa.w +
             xb.x * xb.x + xb.y * xb.y + xb.z * xb.z + xb.w * xb.w;

#pragma unroll
  for (int m = 1; m < 64; m <<= 1) {
    d1 += __shfl_xor(d1, m, 64);
    qq += __shfl_xor(qq, m, 64);
    i1 += __shfl_xor(i1, m, 64);
  }

  float d = d1, nn = i1;
  if (need2) {
    const float4* p2 = (const float4*)(items + (size_t)c2i * CD);
    float4 ya = p2[lane * 2], yb = p2[lane * 2 + 1];
    float d2 = qa.x * ya.x + qa.y * ya.y + qa.z * ya.z + qa.w * ya.w +
               qb.x * yb.x + qb.y * yb.y + qb.z * yb.z + qb.w * yb.w;
    float i2 = ya.x * ya.x + ya.y * ya.y + ya.z * ya.z + ya.w * ya.w +
               yb.x * yb.x + yb.y * yb.y + yb.z * yb.z + yb.w * yb.w;
#pragma unroll
    for (int m = 1; m < 64; m <<= 1) {
      d2 += __shfl_xor(d2, m, 64);
      i2 += __shfl_xor(i2, m, 64);
    }
    const bool use2 = (d2 > d1) || (d2 == d1 && c2i < c1i);
    d  = use2 ? d2 : d1;
    nn = use2 ? i2 : i1;
  }

  if (lane == 0) {
    float nq = fmaxf(sqrtf(qq), 1e-12f);
    float np = fmaxf(sqrtf(nn), 1e-12f);
    out[qrow] = -(d / (nq * np));
  }
}

// ---------------------------------------------------------------------------
extern "C" void kernel_launch(void* const* d_in, const int* in_sizes, int n_in,
                              void* d_out, int out_size, void* d_ws,
                              size_t ws_size, hipStream_t stream) {
  const float* q  = (const float*)d_in[0];
  const float* it = (const float*)d_in[1];
  char* ws = (char*)d_ws;
  float* out = (float*)d_out;

  const int total = TQ * CD / 4 + MI * CD / 8;
  convert_kernel<<<(total + 255) / 256, 256, 0, stream>>>(q, it, ws);
  dim3 grid(TQ / BM, NIS);
  score_kernel<<<grid, 512, 0, stream>>>(ws);
  rescue_kernel<<<TQ / 4, 256, 0, stream>>>(q, it, ws, out);
}

// Round 12
// 184.089 us; speedup vs baseline: 1.2896x; 1.2896x over previous
//
#include <hip/hip_runtime.h>

// ---------------------------------------------------------------------------
// NearestSim: out[t] = -cos(q_t, items[argmax_j q_t . items_j])
// T=16384, M=4096, C=512, fp32 in/out.
// R23 = R22 (128q x 256i block, 8 waves 2x4, wave-pair B-line sharing via
//       L1, K-sub-phase dbuf staging, counted vmcnt barriers, med3 +
//       ds_swizzle epilogue) with __launch_bounds__(512, 2):
//  - R22's (512,4) cap = 128 UNIFIED regs/wave (gfx950 unified VGPR/AGPR) —
//    64 acc left only 64 for everything else -> spill (WRITE 244MB), the
//    same failure mode as R15. The L1-sharing theory was never tested.
//  - (512,2) = 256 regs/wave: same per-wave footprint as R20's clean 96+64.
//    1 block/CU = 8 waves/CU; R20 showed that costs only ~2% vs 12 waves.
//  - Hypothesis under test: block B footprint/kstep = 16KB fits 32KB L1;
//    wave pair (wr=0/1, same wc) reads identical B lines -> L2 B-request
//    volume halves (1GB -> 0.5GB). If sustained-L2 delivery is binding
//    (the invariant across R14-R21's 85us plateau), score drops to ~65us.
// ---------------------------------------------------------------------------

#define TQ 16384
#define MI 4096
#define CD 512
#define NIS 16          // item splits; block covers 256 items
#define BM 128          // block query rows (2 x 64 per wave-row)

typedef _Float16 half8   __attribute__((ext_vector_type(8)));
typedef _Float16 half4_t __attribute__((ext_vector_type(4)));
typedef float    float4t __attribute__((ext_vector_type(4)));

// workspace layout (bytes)
#define QH_OFF   (0u)
#define QH_BYTES ((unsigned)TQ * CD * 2u)          // 16 MB fp16 queries (row-major)
#define IH_OFF   (QH_OFF + QH_BYTES)
#define IH_BYTES ((unsigned)MI * CD * 2u)          // 4 MB fp16 items (fragment order)
#define PART_OFF (IH_OFF + IH_BYTES)
#define PART_BYTES ((unsigned)TQ * 64u * 8u)       // 8 MB: 64 float2 / query
// total 28 MB

__device__ __forceinline__ void lds_load16(const void* g, void* l) {
  __builtin_amdgcn_global_load_lds(
      (const __attribute__((address_space(1))) void*)g,
      (__attribute__((address_space(3))) void*)l, 16, 0, 0);
}

template <int SWZ>
__device__ __forceinline__ float swz_f(float x) {
  return __int_as_float(__builtin_amdgcn_ds_swizzle(__float_as_int(x), SWZ));
}

// ---------------- kernel 1: fp32 -> fp16 conversion -------------------------
// Q: row-major half4 copy. Items: fragment order (chunk = (tile16*16+kk)*64
// + lane; lane = quad*16+l15 holds row tile16*16+l15, cols kk*32+quad*8..+8).
__global__ __launch_bounds__(256) void convert_kernel(
    const float* __restrict__ q, const float* __restrict__ it,
    char* __restrict__ ws) {
  const int idx = blockIdx.x * 256 + threadIdx.x;
  const int QV = TQ * CD / 4;   // Q: one half4 per thread
  const int IC = MI * CD / 8;   // items: one 16B chunk per thread
  if (idx < QV) {
    float4 v = ((const float4*)q)[idx];
    half4_t h = {(_Float16)v.x, (_Float16)v.y, (_Float16)v.z, (_Float16)v.w};
    ((half4_t*)(ws + QH_OFF))[idx] = h;
  }
  const int ic = idx - QV;
  if (ic >= 0 && ic < IC) {
    const int tile = ic >> 10;          // 1024 chunks per 16-row tile
    const int rem  = ic & 1023;
    const int kk   = rem >> 6;
    const int lane = rem & 63;
    const int row  = tile * 16 + (lane & 15);
    const int col  = kk * 32 + (lane >> 4) * 8;
    const float4* s = (const float4*)(it + (size_t)row * CD + col);
    float4 v0 = s[0], v1 = s[1];
    half8 h = {(_Float16)v0.x, (_Float16)v0.y, (_Float16)v0.z, (_Float16)v0.w,
               (_Float16)v1.x, (_Float16)v1.y, (_Float16)v1.z, (_Float16)v1.w};
    *(half8*)(ws + IH_OFF + (size_t)ic * 16) = h;
  }
}

// ---------------- kernel 2: pipelined fused GEMM + packed top-2 -------------
// grid (TQ/128, NIS), block 512 = 8 waves: wr = wave>>2 (q-half), wc = wave&3
// (item group). Wave tile 64q x 64i (4x4 MFMAs of 16x16x32, 64 acc).
// A image: 4 sub-phases of K=128, 128 rows x 256B = 32KB each, dbuf 64KB.
// B direct global; wave pairs (wr=0/1) share B lines via L1.
// LDS image (per phase buf): row r (0..127) at r*256; 16 chunks of 16B per
// row; phys chunk = logical c ^ (r&15).
// Staging (4 instr/phase): instr j, thread t -> dest = buf*32768+j*8192+t*16
//   row = j*32 + (t>>4), phys chunk = t&15,
//   logical c = (t&15) ^ (row&15) = (t&15) ^ ((t>>4)&15)  [j*32 ≡ 0 mod 16].
__global__ __launch_bounds__(512, 2) void score_kernel(char* __restrict__ ws) {
  __shared__ __align__(16) char sA[2][32768];  // 64 KB total

  const int tid  = threadIdx.x;
  const int lane = tid & 63;
  const int wave = tid >> 6;       // 0..7
  const int quad = lane >> 4;
  const int l15  = lane & 15;
  const int wr   = wave >> 2;      // q-half 0/1
  const int wc   = wave & 3;       // item group 0..3
  const int qtile = blockIdx.x;    // 0..127; XCD = qtile%8
  const int isplit = blockIdx.y;

  // staging source base: + j*32768 + phase*256
  const char* Qbase = ws + QH_OFF + (size_t)qtile * BM * 1024;
  const char* gQ = Qbase + (tid >> 4) * 1024 +
                   (((tid & 15) ^ ((tid >> 4) & 15)) * 16);
  const int ldst = tid * 16;  // + buf*32768 + j*8192

  // B stream: tile(ni) = isplit*16 + wc*4 + ni  (wr pair shares these lines)
  const char* Ibase = ws + IH_OFF;
  int bOff[4];
#pragma unroll
  for (int ni = 0; ni < 4; ++ni)
    bOff[ni] = ((isplit * 16 + wc * 4 + ni) << 14) + lane * 16;

  // A fragment: byte = buf*32768 + wr*16384 + mi*4096 + l15*256
  //                    + ((kl*4+quad) ^ l15)*16
  const int aBase = wr * 16384 + l15 * 256;

  float4t acc[4][4];
#pragma unroll
  for (int mi = 0; mi < 4; ++mi)
#pragma unroll
    for (int ni = 0; ni < 4; ++ni) acc[mi][ni] = (float4t){0.f, 0.f, 0.f, 0.f};

  half8 aC[4], aN[4], b0[4], b1[4], b2[4];

#define STAGE(ph, buf)                                                    \
  {                                                                       \
    _Pragma("unroll") for (int j = 0; j < 4; ++j)                         \
      lds_load16(gQ + j * 32768 + (ph) * 256,                             \
                 (char*)sA + (buf) * 32768 + j * 8192 + ldst);            \
  }

  STAGE(0, 0);
  STAGE(1, 1);
  __builtin_amdgcn_sched_barrier(0);  // pin: B prologue issues AFTER staging

  // B prologue: k0 -> b0, k1 -> b1, k2 -> b2 (12 loads, stay in flight)
#pragma unroll
  for (int ni = 0; ni < 4; ++ni) b0[ni] = *(const half8*)(Ibase + bOff[ni]);
#pragma unroll
  for (int ni = 0; ni < 4; ++ni)
    b1[ni] = *(const half8*)(Ibase + bOff[ni] + 1024);
#pragma unroll
  for (int ni = 0; ni < 4; ++ni)
    b2[ni] = *(const half8*)(Ibase + bOff[ni] + 2048);

  // 20 outstanding; vmcnt(16) drains the 4 oldest = stage(0).
  asm volatile("s_waitcnt vmcnt(16)\n\ts_barrier" ::: "memory");

  // WB: stage group is older than the 16 B loads of the preceding KPHASE;
  // vmcnt(12) -> stage done, 12 newest B prefetches stay in flight.
#define WB() asm volatile("s_waitcnt vmcnt(12)\n\ts_barrier" ::: "memory")

#define KPHASE(ph, buf)                                                   \
  {                                                                       \
    const char* sB = (const char*)sA + (buf) * 32768 + aBase;             \
    _Pragma("unroll") for (int mi = 0; mi < 4; ++mi)                      \
      aC[mi] = *(const half8*)(sB + mi * 4096 + ((quad ^ l15) << 4));     \
    _Pragma("unroll") for (int kl = 0; kl < 4; ++kl) {                    \
      const int kk = (ph) * 4 + kl;                                       \
      half8* bs = (kk % 3 == 0) ? b0 : (kk % 3 == 1) ? b1 : b2;           \
      if (kl + 1 < 4) {   /* a-frags for next kstep (separate regs) */    \
        const int cN = ((((kl + 1) << 2) + quad) ^ l15) << 4;             \
        _Pragma("unroll") for (int mi = 0; mi < 4; ++mi)                  \
          aN[mi] = *(const half8*)(sB + mi * 4096 + cN);                  \
      }                                                                   \
      __builtin_amdgcn_s_setprio(1);                                      \
      _Pragma("unroll") for (int mi = 0; mi < 4; ++mi)                    \
        _Pragma("unroll") for (int ni = 0; ni < 4; ++ni)                  \
          acc[mi][ni] = __builtin_amdgcn_mfma_f32_16x16x32_f16(           \
              aC[mi], bs[ni], acc[mi][ni], 0, 0, 0);                      \
      __builtin_amdgcn_s_setprio(0);                                      \
      if (kk + 3 < 16) {  /* depth-3: refill the set just consumed */     \
        _Pragma("unroll") for (int ni = 0; ni < 4; ++ni)                  \
          bs[ni] = *(const half8*)(Ibase + bOff[ni] + 3072);              \
      }                                                                   \
      if (kl + 1 < 4) {                                                   \
        _Pragma("unroll") for (int x = 0; x < 4; ++x) aC[x] = aN[x];      \
      }                                                                   \
      _Pragma("unroll") for (int ni = 0; ni < 4; ++ni) bOff[ni] += 1024;  \
    }                                                                     \
  }

  KPHASE(0, 0);
  WB();             // stage(1) done; newest B prefetches stay in flight
  STAGE(2, 0);      // b0 image free: all waves passed the barrier
  KPHASE(1, 1);
  WB();             // stage(2) done
  STAGE(3, 1);
  KPHASE(2, 0);
  WB();             // stage(3) done
  KPHASE(3, 1);

#undef KPHASE
#undef WB
#undef STAGE

  // ---- epilogue: packed (score | 12-bit global idx) top-2 per query row ----
  // C row = quad*4+r (within wave's 64q), col = l15.
  // item = isplit*256 + wc*64 + ni*16 + l15.
  float t1[16], t2[16];

  const int locBase = isplit * 256 + wc * 64 + l15;
#pragma unroll
  for (int ni = 0; ni < 4; ++ni) {
    const int loc = locBase + ni * 16;
#pragma unroll
    for (int mi = 0; mi < 4; ++mi) {
#pragma unroll
      for (int r = 0; r < 4; ++r) {
        const int s = mi * 4 + r;
        const float pv = __int_as_float(
            (__float_as_int(acc[mi][ni][r]) & 0xFFFFF000) | loc);
        if (ni == 0) {
          t1[s] = pv;
          t2[s] = -1e30f;
        } else {
          t2[s] = __builtin_amdgcn_fmed3f(pv, t1[s], t2[s]);
          t1[s] = fmaxf(t1[s], pv);
        }
      }
    }
  }

  // 4-step butterfly across the 16-lane l15 group via ds_swizzle xor
  // patterns (BitMode: offset = (xor<<10)|0x1F). Disjoint partner sets:
  //   t2' = med3(t1, o1, max(t2, o2)) = max(min(t1,o1), max(t2,o2)).
#define BSTEP(SWZ)                                                       \
  {                                                                      \
    _Pragma("unroll") for (int s = 0; s < 16; ++s) {                     \
      const float o1 = swz_f<SWZ>(t1[s]);                                \
      const float o2 = swz_f<SWZ>(t2[s]);                                \
      t2[s] = __builtin_amdgcn_fmed3f(t1[s], o1, fmaxf(t2[s], o2));      \
      t1[s] = fmaxf(t1[s], o1);                                          \
    }                                                                    \
  }
  BSTEP(0x041F)   // xor 1
  BSTEP(0x081F)   // xor 2
  BSTEP(0x101F)   // xor 4
  BSTEP(0x201F)   // xor 8
#undef BSTEP

  // writer: l15 == 0; entry = isplit*4 + wc. 64 entries per query.
  if (l15 == 0) {
    float2* part = (float2*)(ws + PART_OFF);
    const int e = isplit * 4 + wc;
#pragma unroll
    for (int s = 0; s < 16; ++s) {
      const int qrow = qtile * BM + wr * 64 + (s >> 2) * 16 + quad * 4 +
                       (s & 3);
      part[(size_t)qrow * 64 + e] = make_float2(t1[s], t2[s]);
    }
  }
}

// ---------------- kernel 3: merge partials + exact fp32 rescue --------------
// one wave per query: 64 packed entries (1/lane) -> global fp16 top-2.
// If the packed gap exceeds 0.25 (>>5 sigma of fp16+quant score error),
// candidate 1 is certainly the true argmax: skip the 2nd gather entirely
// (wave-uniform branch). Otherwise exact fp32 re-score of both.
__global__ __launch_bounds__(256) void rescue_kernel(
    const float* __restrict__ q, const float* __restrict__ items,
    const char* __restrict__ ws, float* __restrict__ out) {
  const int wave = threadIdx.x >> 6;
  const int lane = threadIdx.x & 63;
  const int qrow = blockIdx.x * 4 + wave;

  const float2* part = (const float2*)(ws + PART_OFF);
  float2 ent = part[(size_t)qrow * 64 + lane];  // coalesced 512B burst
  float t1 = ent.x, t2 = ent.y;

#pragma unroll
  for (int m = 1; m < 64; m <<= 1) {
    const float o1 = __shfl_xor(t1, m, 64);
    const float o2 = __shfl_xor(t2, m, 64);
    const float mn = fminf(t1, o1);
    t1 = fmaxf(t1, o1);
    t2 = fmaxf(fmaxf(t2, o2), mn);
  }
  const int c1i = __float_as_int(t1) & 0xFFF;
  const int c2i = __float_as_int(t2) & 0xFFF;
  const bool need2 = (t1 - t2) < 0.25f;   // wave-uniform

  const float4* qp = (const float4*)(q + (size_t)qrow * CD);
  const float4* p1 = (const float4*)(items + (size_t)c1i * CD);
  float4 qa = qp[lane * 2], qb = qp[lane * 2 + 1];
  float4 xa = p1[lane * 2], xb = p1[lane * 2 + 1];

  float d1 = qa.x * xa.x + qa.y * xa.y + qa.z * xa.z + qa.w * xa.w +
             qb.x * xb.x + qb.y * xb.y + qb.z * xb.z + qb.w * xb.w;
  float qq = qa.x * qa.x + qa.y * qa.y + qa.z * qa.z + qa.w * qa.w +
             qb.x * qb.x + qb.y * qb.y + qb.z * qb.z + qb.w * qb.w;
  float i1 = xa.x * xa.x + xa.y * xa.y + xa.z * xa.z + xa.w * xa.w +
             xb.x * xb.x + xb.y * xb.y + xb.z * xb.z + xb.w * xb.w;

#pragma unroll
  for (int m = 1; m < 64; m <<= 1) {
    d1 += __shfl_xor(d1, m, 64);
    qq += __shfl_xor(qq, m, 64);
    i1 += __shfl_xor(i1, m, 64);
  }

  float d = d1, nn = i1;
  if (need2) {
    const float4* p2 = (const float4*)(items + (size_t)c2i * CD);
    float4 ya = p2[lane * 2], yb = p2[lane * 2 + 1];
    float d2 = qa.x * ya.x + qa.y * ya.y + qa.z * ya.z + qa.w * ya.w +
               qb.x * yb.x + qb.y * yb.y + qb.z * yb.z + qb.w * yb.w;
    float i2 = ya.x * ya.x + ya.y * ya.y + ya.z * ya.z + ya.w * ya.w +
               yb.x * yb.x + yb.y * yb.y + yb.z * yb.z + yb.w * yb.w;
#pragma unroll
    for (int m = 1; m < 64; m <<= 1) {
      d2 += __shfl_xor(d2, m, 64);
      i2 += __shfl_xor(i2, m, 64);
    }
    const bool use2 = (d2 > d1) || (d2 == d1 && c2i < c1i);
    d  = use2 ? d2 : d1;
    nn = use2 ? i2 : i1;
  }

  if (lane == 0) {
    float nq = fmaxf(sqrtf(qq), 1e-12f);
    float np = fmaxf(sqrtf(nn), 1e-12f);
    out[qrow] = -(d / (nq * np));
  }
}

// ---------------------------------------------------------------------------
extern "C" void kernel_launch(void* const* d_in, const int* in_sizes, int n_in,
                              void* d_out, int out_size, void* d_ws,
                              size_t ws_size, hipStream_t stream) {
  const float* q  = (const float*)d_in[0];
  const float* it = (const float*)d_in[1];
  char* ws = (char*)d_ws;
  float* out = (float*)d_out;

  const int total = TQ * CD / 4 + MI * CD / 8;
  convert_kernel<<<(total + 255) / 256, 256, 0, stream>>>(q, it, ws);
  dim3 grid(TQ / BM, NIS);
  score_kernel<<<grid, 512, 0, stream>>>(ws);
  rescue_kernel<<<TQ / 4, 256, 0, stream>>>(q, it, ws, out);
}

// Round 13
// 168.587 us; speedup vs baseline: 1.4082x; 1.0920x over previous
//
#include <hip/hip_runtime.h>

// ---------------------------------------------------------------------------
// NearestSim: out[t] = -cos(q_t, items[argmax_j q_t . items_j])
// T=16384, M=4096, C=512, fp32 in/out.
// R24 = 128q-per-WAVE restructure (the one invariant never changed):
//  - every prior schedule kept 64 q-rows/wave -> per-wave B request count
//    fixed (4 dwordx4/kstep x 16384 wave-tiles ~= 1M VMEM instrs). All of
//    {occupancy, depth, barriers, XCD, L1-sharing} plateaued at 85-102us /
//    MfmaUtil ~35% because none reduced it. R23 proved bytes aren't binding
//    (FETCH 76MB, slower); per-request throughput fits all data points.
//  - wave tile 128q x 64i (8x4 MFMAs, 128 acc): wave-tiles 16384 -> 8192,
//    B requests HALVE. MFMA window/kstep doubles to ~310cyc (better cover).
//  - block 256thr = 4 waves = 128q x 256i; A image 128x512B = 64KB/phase,
//    R14's proven 2-phase staging; 2 blocks/CU = 8 waves.
//  - (256,2) = 256 unified regs: 128 acc + 32 aC (no A-prefetch; 2 waves/
//    SIMD TLP covers ds latency) + 48 B (depth-2 rotation) + ~25 addr = 233.
//  - merge entries unchanged (64/query): e = isplit*4 + wave.
// ---------------------------------------------------------------------------

#define TQ 16384
#define MI 4096
#define CD 512
#define NIS 16          // item splits; block covers 256 items
#define BM 128          // block query rows (= wave q-rows)

typedef _Float16 half8   __attribute__((ext_vector_type(8)));
typedef _Float16 half4_t __attribute__((ext_vector_type(4)));
typedef float    float4t __attribute__((ext_vector_type(4)));

// workspace layout (bytes)
#define QH_OFF   (0u)
#define QH_BYTES ((unsigned)TQ * CD * 2u)          // 16 MB fp16 queries (row-major)
#define IH_OFF   (QH_OFF + QH_BYTES)
#define IH_BYTES ((unsigned)MI * CD * 2u)          // 4 MB fp16 items (fragment order)
#define PART_OFF (IH_OFF + IH_BYTES)
#define PART_BYTES ((unsigned)TQ * 64u * 8u)       // 8 MB: 64 float2 / query
// total 28 MB

__device__ __forceinline__ void lds_load16(const void* g, void* l) {
  __builtin_amdgcn_global_load_lds(
      (const __attribute__((address_space(1))) void*)g,
      (__attribute__((address_space(3))) void*)l, 16, 0, 0);
}

template <int SWZ>
__device__ __forceinline__ float swz_f(float x) {
  return __int_as_float(__builtin_amdgcn_ds_swizzle(__float_as_int(x), SWZ));
}

// ---------------- kernel 1: fp32 -> fp16 conversion -------------------------
// Q: row-major half4 copy. Items: fragment order (chunk = (tile16*16+kk)*64
// + lane; lane = quad*16+l15 holds row tile16*16+l15, cols kk*32+quad*8..+8).
__global__ __launch_bounds__(256) void convert_kernel(
    const float* __restrict__ q, const float* __restrict__ it,
    char* __restrict__ ws) {
  const int idx = blockIdx.x * 256 + threadIdx.x;
  const int QV = TQ * CD / 4;   // Q: one half4 per thread
  const int IC = MI * CD / 8;   // items: one 16B chunk per thread
  if (idx < QV) {
    float4 v = ((const float4*)q)[idx];
    half4_t h = {(_Float16)v.x, (_Float16)v.y, (_Float16)v.z, (_Float16)v.w};
    ((half4_t*)(ws + QH_OFF))[idx] = h;
  }
  const int ic = idx - QV;
  if (ic >= 0 && ic < IC) {
    const int tile = ic >> 10;          // 1024 chunks per 16-row tile
    const int rem  = ic & 1023;
    const int kk   = rem >> 6;
    const int lane = rem & 63;
    const int row  = tile * 16 + (lane & 15);
    const int col  = kk * 32 + (lane >> 4) * 8;
    const float4* s = (const float4*)(it + (size_t)row * CD + col);
    float4 v0 = s[0], v1 = s[1];
    half8 h = {(_Float16)v0.x, (_Float16)v0.y, (_Float16)v0.z, (_Float16)v0.w,
               (_Float16)v1.x, (_Float16)v1.y, (_Float16)v1.z, (_Float16)v1.w};
    *(half8*)(ws + IH_OFF + (size_t)ic * 16) = h;
  }
}

// ---------------- kernel 2: 128q-per-wave fused GEMM + packed top-2 ---------
// grid (TQ/128, NIS), block 256 = 4 waves; wave tile 128q x 64i (8x4 MFMAs
// of 16x16x32, 128 acc). A image: 2 phases of K=256, 128 rows x 512B = 64KB.
// B direct global, depth-2 rotation (bC/bN/bN2), 4 loads/kstep.
// LDS image (per phase): row r (0..127) at r*512; 32 chunks of 16B;
// phys chunk = logical c ^ (r&15)  -> a-frag b128 reads conflict-free.
// Staging (16 instr): instr j, thread t -> dest = j*4096 + t*16
//   row = j*8 + (t>>5), phys chunk = t&31,
//   logical c = (t&31) ^ (row&15) = (t&31) ^ (t>>5) ^ (8*(j&1)).
__global__ __launch_bounds__(256, 2) void score_kernel(char* __restrict__ ws) {
  __shared__ __align__(16) char sA[65536];  // 64 KB, re-staged per phase

  const int tid  = threadIdx.x;
  const int lane = tid & 63;
  const int wave = tid >> 6;       // 0..3 (item group)
  const int quad = lane >> 4;
  const int l15  = lane & 15;
  const int qtile = blockIdx.x;    // 0..127; XCD = qtile%8
  const int isplit = blockIdx.y;

  // staging source (two variants by j&1): + (j>>1)*16384 + phase*512
  const char* Qbase = ws + QH_OFF + (size_t)qtile * BM * 1024;
  const char* gA = Qbase + (tid >> 5) * 1024 +
                   (((tid & 31) ^ (tid >> 5)) << 4);
  const char* gB = Qbase + 8192 + (tid >> 5) * 1024 +
                   (((tid & 31) ^ 8 ^ (tid >> 5)) << 4);
  const int ldst = tid * 16;  // + j*4096

  // B stream: tile(ni) = isplit*16 + wave*4 + ni
  const char* Ibase = ws + IH_OFF;
  int bOff[4];
#pragma unroll
  for (int ni = 0; ni < 4; ++ni)
    bOff[ni] = ((isplit * 16 + wave * 4 + ni) << 14) + lane * 16;

  // A fragment: byte = mi*8192 + l15*512 + (((kl*4+quad) ^ l15) << 4)
  const int aRow = l15 * 512;

  float4t acc[8][4];
#pragma unroll
  for (int mi = 0; mi < 8; ++mi)
#pragma unroll
    for (int ni = 0; ni < 4; ++ni) acc[mi][ni] = (float4t){0.f, 0.f, 0.f, 0.f};

  half8 aC[8], bC[4], bN[4], bN2[4];

#define STAGE(ph)                                                         \
  {                                                                       \
    _Pragma("unroll") for (int j = 0; j < 16; ++j)                        \
      lds_load16(((j & 1) ? gB : gA) + (j >> 1) * 16384 + (ph) * 512,     \
                 sA + j * 4096 + ldst);                                   \
  }

  STAGE(0);
  __builtin_amdgcn_sched_barrier(0);  // pin: B prologue issues AFTER staging

  // B prologue: k0 -> bC, k1 -> bN (8 loads, stay in flight)
#pragma unroll
  for (int ni = 0; ni < 4; ++ni) bC[ni] = *(const half8*)(Ibase + bOff[ni]);
#pragma unroll
  for (int ni = 0; ni < 4; ++ni)
    bN[ni] = *(const half8*)(Ibase + bOff[ni] + 1024);

  // 24 outstanding; vmcnt(8) drains the 16 oldest = all stage loads,
  // leaves the 8 B-prologue loads in flight.
  asm volatile("s_waitcnt vmcnt(8)\n\ts_barrier" ::: "memory");

#define KPHASE(ph)                                                        \
  {                                                                       \
    _Pragma("unroll") for (int kl = 0; kl < 8; ++kl) {                    \
      const int kkg = (ph) * 8 + kl;                                      \
      if (kkg + 2 < 16) {  /* depth-2 B prefetch */                       \
        _Pragma("unroll") for (int ni = 0; ni < 4; ++ni)                  \
          bN2[ni] = *(const half8*)(Ibase + bOff[ni] + 2048);             \
      }                                                                   \
      {  /* a-frags for this kstep (no prefetch; TLP covers ds latency) */\
        const int c = (((kl << 2) + quad) ^ l15) << 4;                    \
        _Pragma("unroll") for (int mi = 0; mi < 8; ++mi)                  \
          aC[mi] = *(const half8*)(sA + mi * 8192 + aRow + c);            \
      }                                                                   \
      __builtin_amdgcn_s_setprio(1);                                      \
      _Pragma("unroll") for (int mi = 0; mi < 8; ++mi)                    \
        _Pragma("unroll") for (int ni = 0; ni < 4; ++ni)                  \
          acc[mi][ni] = __builtin_amdgcn_mfma_f32_16x16x32_f16(           \
              aC[mi], bC[ni], acc[mi][ni], 0, 0, 0);                      \
      __builtin_amdgcn_s_setprio(0);                                      \
      _Pragma("unroll") for (int x = 0; x < 4; ++x) bC[x] = bN[x];        \
      if (kkg + 2 < 16) {                                                 \
        _Pragma("unroll") for (int x = 0; x < 4; ++x) bN[x] = bN2[x];     \
      }                                                                   \
      _Pragma("unroll") for (int ni = 0; ni < 4; ++ni) bOff[ni] += 1024;  \
    }                                                                     \
  }

  KPHASE(0);
  __syncthreads();   // all phase-0 a-reads done (drains k8/k9 B: needed now)
  STAGE(1);
  __syncthreads();   // staged image visible
  KPHASE(1);

#undef KPHASE
#undef STAGE

  // ---- epilogue: packed (score | 12-bit global idx) top-2 per query row ----
  // C row = mi*16 + quad*4 + r, col = l15.
  // item = isplit*256 + wave*64 + ni*16 + l15.
  float t1[32], t2[32];

  const int locBase = isplit * 256 + wave * 64 + l15;
#pragma unroll
  for (int ni = 0; ni < 4; ++ni) {
    const int loc = locBase + ni * 16;
#pragma unroll
    for (int mi = 0; mi < 8; ++mi) {
#pragma unroll
      for (int r = 0; r < 4; ++r) {
        const int s = mi * 4 + r;
        const float pv = __int_as_float(
            (__float_as_int(acc[mi][ni][r]) & 0xFFFFF000) | loc);
        if (ni == 0) {
          t1[s] = pv;
          t2[s] = -1e30f;
        } else {
          t2[s] = __builtin_amdgcn_fmed3f(pv, t1[s], t2[s]);
          t1[s] = fmaxf(t1[s], pv);
        }
      }
    }
  }

  // 4-step butterfly across the 16-lane l15 group via ds_swizzle xor
  // patterns (BitMode: offset = (xor<<10)|0x1F). Disjoint partner sets:
  //   t2' = med3(t1, o1, max(t2, o2)) = max(min(t1,o1), max(t2,o2)).
#define BSTEP(SWZ)                                                       \
  {                                                                      \
    _Pragma("unroll") for (int s = 0; s < 32; ++s) {                     \
      const float o1 = swz_f<SWZ>(t1[s]);                                \
      const float o2 = swz_f<SWZ>(t2[s]);                                \
      t2[s] = __builtin_amdgcn_fmed3f(t1[s], o1, fmaxf(t2[s], o2));      \
      t1[s] = fmaxf(t1[s], o1);                                          \
    }                                                                    \
  }
  BSTEP(0x041F)   // xor 1
  BSTEP(0x081F)   // xor 2
  BSTEP(0x101F)   // xor 4
  BSTEP(0x201F)   // xor 8
#undef BSTEP

  // writer: l15 == 0; entry = isplit*4 + wave. 64 entries per query.
  if (l15 == 0) {
    float2* part = (float2*)(ws + PART_OFF);
    const int e = isplit * 4 + wave;
#pragma unroll
    for (int s = 0; s < 32; ++s) {
      const int qrow = qtile * BM + (s >> 2) * 16 + quad * 4 + (s & 3);
      part[(size_t)qrow * 64 + e] = make_float2(t1[s], t2[s]);
    }
  }
}

// ---------------- kernel 3: merge partials + exact fp32 rescue --------------
// one wave per query: 64 packed entries (1/lane) -> global fp16 top-2.
// If the packed gap exceeds 0.25 (>>5 sigma of fp16+quant score error),
// candidate 1 is certainly the true argmax: skip the 2nd gather entirely
// (wave-uniform branch). Otherwise exact fp32 re-score of both.
__global__ __launch_bounds__(256) void rescue_kernel(
    const float* __restrict__ q, const float* __restrict__ items,
    const char* __restrict__ ws, float* __restrict__ out) {
  const int wave = threadIdx.x >> 6;
  const int lane = threadIdx.x & 63;
  const int qrow = blockIdx.x * 4 + wave;

  const float2* part = (const float2*)(ws + PART_OFF);
  float2 ent = part[(size_t)qrow * 64 + lane];  // coalesced 512B burst
  float t1 = ent.x, t2 = ent.y;

#pragma unroll
  for (int m = 1; m < 64; m <<= 1) {
    const float o1 = __shfl_xor(t1, m, 64);
    const float o2 = __shfl_xor(t2, m, 64);
    const float mn = fminf(t1, o1);
    t1 = fmaxf(t1, o1);
    t2 = fmaxf(fmaxf(t2, o2), mn);
  }
  const int c1i = __float_as_int(t1) & 0xFFF;
  const int c2i = __float_as_int(t2) & 0xFFF;
  const bool need2 = (t1 - t2) < 0.25f;   // wave-uniform

  const float4* qp = (const float4*)(q + (size_t)qrow * CD);
  const float4* p1 = (const float4*)(items + (size_t)c1i * CD);
  float4 qa = qp[lane * 2], qb = qp[lane * 2 + 1];
  float4 xa = p1[lane * 2], xb = p1[lane * 2 + 1];

  float d1 = qa.x * xa.x + qa.y * xa.y + qa.z * xa.z + qa.w * xa.w +
             qb.x * xb.x + qb.y * xb.y + qb.z * xb.z + qb.w * xb.w;
  float qq = qa.x * qa.x + qa.y * qa.y + qa.z * qa.z + qa.w * qa.w +
             qb.x * qb.x + qb.y * qb.y + qb.z * qb.z + qb.w * qb.w;
  float i1 = xa.x * xa.x + xa.y * xa.y + xa.z * xa.z + xa.w * xa.w +
             xb.x * xb.x + xb.y * xb.y + xb.z * xb.z + xb.w * xb.w;

#pragma unroll
  for (int m = 1; m < 64; m <<= 1) {
    d1 += __shfl_xor(d1, m, 64);
    qq += __shfl_xor(qq, m, 64);
    i1 += __shfl_xor(i1, m, 64);
  }

  float d = d1, nn = i1;
  if (need2) {
    const float4* p2 = (const float4*)(items + (size_t)c2i * CD);
    float4 ya = p2[lane * 2], yb = p2[lane * 2 + 1];
    float d2 = qa.x * ya.x + qa.y * ya.y + qa.z * ya.z + qa.w * ya.w +
               qb.x * yb.x + qb.y * yb.y + qb.z * yb.z + qb.w * yb.w;
    float i2 = ya.x * ya.x + ya.y * ya.y + ya.z * ya.z + ya.w * ya.w +
               yb.x * yb.x + yb.y * yb.y + yb.z * yb.z + yb.w * yb.w;
#pragma unroll
    for (int m = 1; m < 64; m <<= 1) {
      d2 += __shfl_xor(d2, m, 64);
      i2 += __shfl_xor(i2, m, 64);
    }
    const bool use2 = (d2 > d1) || (d2 == d1 && c2i < c1i);
    d  = use2 ? d2 : d1;
    nn = use2 ? i2 : i1;
  }

  if (lane == 0) {
    float nq = fmaxf(sqrtf(qq), 1e-12f);
    float np = fmaxf(sqrtf(nn), 1e-12f);
    out[qrow] = -(d / (nq * np));
  }
}

// ---------------------------------------------------------------------------
extern "C" void kernel_launch(void* const* d_in, const int* in_sizes, int n_in,
                              void* d_out, int out_size, void* d_ws,
                              size_t ws_size, hipStream_t stream) {
  const float* q  = (const float*)d_in[0];
  const float* it = (const float*)d_in[1];
  char* ws = (char*)d_ws;
  float* out = (float*)d_out;

  const int total = TQ * CD / 4 + MI * CD / 8;
  convert_kernel<<<(total + 255) / 256, 256, 0, stream>>>(q, it, ws);
  dim3 grid(TQ / BM, NIS);
  score_kernel<<<grid, 256, 0, stream>>>(ws);
  rescue_kernel<<<TQ / 4, 256, 0, stream>>>(q, it, ws, out);
}